// Round 1
// baseline (558.582 us; speedup 1.0000x reference)
//
#include <hip/hip_runtime.h>
#include <math.h>

#define NB 16384   // batch
#define ND 128     // d_model
#define NS 5       // negatives

__global__ __launch_bounds__(256) void ws_negsamp_kernel(
    const float* __restrict__ h,
    const float* __restrict__ emb,
    const int*   __restrict__ tgt,
    const int*   __restrict__ neg,
    float*       __restrict__ out)
{
    const int wave = (blockIdx.x * blockDim.x + threadIdx.x) >> 6;
    const int lane = threadIdx.x & 63;
    if (wave >= NB) return;
    const int row = wave;

    // h row: lane i holds elements [2i, 2i+1] -> one 512B coalesced wave load
    const float2 hv = *reinterpret_cast<const float2*>(h + (size_t)row * ND + lane * 2);

    // all 6 indices up front so the 6 gathers can be issued independently
    int idx[6];
    idx[0] = tgt[row];
#pragma unroll
    for (int s = 0; s < NS; ++s) idx[s + 1] = neg[row * NS + s];

    float myres = 0.0f;
#pragma unroll
    for (int j = 0; j < 6; ++j) {
        const float2 ev =
            *reinterpret_cast<const float2*>(emb + (size_t)idx[j] * ND + lane * 2);
        float sum = hv.x * ev.x + hv.y * ev.y;
        // 64-lane butterfly reduction
#pragma unroll
        for (int off = 32; off >= 1; off >>= 1)
            sum += __shfl_xor(sum, off, 64);
        const float sig = 1.0f / (1.0f + __expf(-sum));
        if (lane == j) myres = sig;   // lane j holds result of sample j
    }

    // output layout (flat, return order): pos_out[NB], pos_label[NB],
    // neg_out[NB*NS], neg_label[NB*NS]
    if (lane == 0) {
        out[row]      = myres;  // pos_out
        out[NB + row] = 1.0f;   // pos_label
    } else if (lane <= NS) {
        const int s = lane - 1;
        out[2 * NB + row * NS + s]           = myres;  // neg_out
        out[2 * NB + NB * NS + row * NS + s] = 0.0f;   // neg_label
    }
}

extern "C" void kernel_launch(void* const* d_in, const int* in_sizes, int n_in,
                              void* d_out, int out_size, void* d_ws, size_t ws_size,
                              hipStream_t stream) {
    const float* h   = (const float*)d_in[0];
    const float* emb = (const float*)d_in[1];
    const int*   tgt = (const int*)d_in[2];
    const int*   neg = (const int*)d_in[3];
    float*       out = (float*)d_out;

    // one wave per row; 4 waves per 256-thread block
    const int blocks = NB / 4;  // 4096
    ws_negsamp_kernel<<<blocks, 256, 0, stream>>>(h, emb, tgt, neg, out);
}

// Round 2
// 558.265 us; speedup vs baseline: 1.0006x; 1.0006x over previous
//
#include <hip/hip_runtime.h>
#include <math.h>

#define NB 16384   // batch
#define ND 128     // d_model
#define NS 5       // negatives

__global__ __launch_bounds__(256) void ws_negsamp_kernel(
    const float* __restrict__ h,
    const float* __restrict__ emb,
    const int*   __restrict__ tgt,
    const int*   __restrict__ neg,
    float*       __restrict__ out)
{
    const int wave = (blockIdx.x * blockDim.x + threadIdx.x) >> 6;
    const int lane = threadIdx.x & 63;
    const int half = lane >> 5;   // which sample of the pair
    const int hl   = lane & 31;   // lane within 32-lane group
    const int row  = wave;

    // h row: each 32-lane half loads the full 512B row as float4 (served from L1/L2)
    const float4 hv = *reinterpret_cast<const float4*>(h + (size_t)row * ND + hl * 4);

    // 6 sample indices (wave-uniform broadcast loads)
    const int i0 = tgt[row];
    const int i1 = neg[row * NS + 0];
    const int i2 = neg[row * NS + 1];
    const int i3 = neg[row * NS + 2];
    const int i4 = neg[row * NS + 3];
    const int i5 = neg[row * NS + 4];

    // per-half sample index for each of the 3 iterations (static unroll, no
    // dynamic register-array indexing -> stays in registers)
    int myidx[3];
    myidx[0] = half ? i1 : i0;   // samples 0,1
    myidx[1] = half ? i3 : i2;   // samples 2,3
    myidx[2] = half ? i5 : i4;   // samples 4,5

#pragma unroll
    for (int j = 0; j < 3; ++j) {
        const int s_abs = 2 * j + half;   // absolute sample id 0..5
        const float4 ev =
            *reinterpret_cast<const float4*>(emb + (size_t)myidx[j] * ND + hl * 4);
        float sum = hv.x * ev.x + hv.y * ev.y + hv.z * ev.z + hv.w * ev.w;
        // 32-lane butterfly (xor offsets 1..16 stay within each half)
#pragma unroll
        for (int off = 16; off >= 1; off >>= 1)
            sum += __shfl_xor(sum, off, 64);
        if (hl == 0) {
            const float sig = 1.0f / (1.0f + __expf(-sum));
            if (s_abs == 0) {
                out[row]      = sig;    // pos_out
                out[NB + row] = 1.0f;   // pos_label
            } else {
                const int s = s_abs - 1;
                out[2 * NB + row * NS + s]           = sig;    // neg_out
                out[2 * NB + NB * NS + row * NS + s] = 0.0f;   // neg_label
            }
        }
    }
}

extern "C" void kernel_launch(void* const* d_in, const int* in_sizes, int n_in,
                              void* d_out, int out_size, void* d_ws, size_t ws_size,
                              hipStream_t stream) {
    const float* h   = (const float*)d_in[0];
    const float* emb = (const float*)d_in[1];
    const int*   tgt = (const int*)d_in[2];
    const int*   neg = (const int*)d_in[3];
    float*       out = (float*)d_out;

    // one wave per row; 4 waves per 256-thread block
    const int blocks = NB / 4;  // 4096
    ws_negsamp_kernel<<<blocks, 256, 0, stream>>>(h, emb, tgt, neg, out);
}